// Round 3
// baseline (14092.033 us; speedup 1.0000x reference)
//
#include <hip/hip_runtime.h>
#include <hip/hip_bf16.h>
#include <cstdint>

typedef _Float16 h2 __attribute__((ext_vector_type(2)));
typedef _Float16 h8 __attribute__((ext_vector_type(8)));

#define S_LEN 512
#define BATCH 64
#define DM    512
#define HID   768

static __device__ __forceinline__ h2 mk2f(float a, float b) {
  h2 t; t.x = (_Float16)a; t.y = (_Float16)b; return t;
}
static __device__ __forceinline__ h2 mk2h(_Float16 a, _Float16 b) {
  h2 t; t.x = a; t.y = b; return t;
}

// ---------------------------------------------------------------------------
// Kernel A: xg[dir] = gather(emb, ids) @ Wi^T + bi   (fp32 in, fp16 out)
// Chunked: covers CH sequence steps per direction, starting at s0_f / s0_b.
// Output layout (chunk-local sl): xg[((sl*96 + chunk)*3 + gate)*512 + u*64 + b]
//   n = gate*768 + chunk*8 + u, so each scan block (8 units) reads 3
//   contiguous 1KB rows per step, b-contiguous.
// ---------------------------------------------------------------------------
__global__ __launch_bounds__(256) void gemm1_kernel(
    const int* __restrict__ ids, const float* __restrict__ emb,
    const float* __restrict__ Wi_f, const float* __restrict__ bi_f,
    const float* __restrict__ Wi_b, const float* __restrict__ bi_b,
    int s0_f, int s0_b,
    _Float16* __restrict__ xg_f, _Float16* __restrict__ xg_b)
{
  const int mt  = blockIdx.x;      // 0..CH/2-1  (local M tiles of 128)
  const int nty = blockIdx.y;      // 0..35
  const int dir = nty / 18;
  const int nt  = nty - dir * 18;  // 0..17   (N = 2304 / 128)
  const float* __restrict__ Wi = dir ? Wi_b : Wi_f;
  const float* __restrict__ bi = dir ? bi_b : bi_f;
  _Float16*   __restrict__ xg  = dir ? xg_b : xg_f;
  const int s0 = dir ? s0_b : s0_f;

  __shared__ int ids_s[128];
  __shared__ _Float16 As[128][38];   // row stride 38 halves -> conflict-light
  __shared__ _Float16 Bs[128][38];

  const int tid = threadIdx.x;
  if (tid < 128) {
    int m = mt * 128 + tid;          // local m = sl*64 + b
    ids_s[tid] = ids[(m & 63) * S_LEN + s0 + (m >> 6)];   // ids[b][s0+sl]
  }

  float acc[8][8];
#pragma unroll
  for (int i = 0; i < 8; ++i)
#pragma unroll
    for (int j = 0; j < 8; ++j) acc[i][j] = 0.f;

  const int tr = tid >> 4, tc = tid & 15;
  const int r0 = tr * 8, c0 = tc * 8;
  const int lr = tid >> 1, lh = tid & 1;

  __syncthreads();

  for (int kt = 0; kt < DM; kt += 32) {
    {
      const float* srcA = emb + (size_t)ids_s[lr] * DM + kt + lh * 16;
      const float* srcB = Wi + (size_t)(nt * 128 + lr) * DM + kt + lh * 16;
      float4 a0 = ((const float4*)srcA)[0], a1 = ((const float4*)srcA)[1];
      float4 a2 = ((const float4*)srcA)[2], a3 = ((const float4*)srcA)[3];
      float4 b0 = ((const float4*)srcB)[0], b1v = ((const float4*)srcB)[1];
      float4 b2v = ((const float4*)srcB)[2], b3 = ((const float4*)srcB)[3];
      h2* da = (h2*)&As[lr][lh * 16];
      h2* db = (h2*)&Bs[lr][lh * 16];
      da[0] = mk2f(a0.x, a0.y);  da[1] = mk2f(a0.z, a0.w);
      da[2] = mk2f(a1.x, a1.y);  da[3] = mk2f(a1.z, a1.w);
      da[4] = mk2f(a2.x, a2.y);  da[5] = mk2f(a2.z, a2.w);
      da[6] = mk2f(a3.x, a3.y);  da[7] = mk2f(a3.z, a3.w);
      db[0] = mk2f(b0.x, b0.y);  db[1] = mk2f(b0.z, b0.w);
      db[2] = mk2f(b1v.x, b1v.y); db[3] = mk2f(b1v.z, b1v.w);
      db[4] = mk2f(b2v.x, b2v.y); db[5] = mk2f(b2v.z, b2v.w);
      db[6] = mk2f(b3.x, b3.y);  db[7] = mk2f(b3.z, b3.w);
    }
    __syncthreads();
#pragma unroll
    for (int kp = 0; kp < 16; ++kp) {
      h2 av[8], bv[8];
#pragma unroll
      for (int i = 0; i < 8; ++i) av[i] = *(const h2*)&As[r0 + i][kp * 2];
#pragma unroll
      for (int j = 0; j < 8; ++j) bv[j] = *(const h2*)&Bs[c0 + j][kp * 2];
#pragma unroll
      for (int i = 0; i < 8; ++i)
#pragma unroll
        for (int j = 0; j < 8; ++j)
          acc[i][j] = __builtin_amdgcn_fdot2(av[i], bv[j], acc[i][j], false);
    }
    __syncthreads();
  }

  float biv[8];
#pragma unroll
  for (int j = 0; j < 8; ++j) biv[j] = bi[nt * 128 + c0 + j];
#pragma unroll
  for (int i = 0; i < 8; ++i) {
    int m = mt * 128 + r0 + i;
    int sl = m >> 6, b = m & 63;     // chunk-local step, batch
#pragma unroll
    for (int j = 0; j < 8; ++j) {
      int n = nt * 128 + c0 + j;
      int gate = n / 768;
      int r768 = n - gate * 768;
      int chunk = r768 >> 3;
      int u = n & 7;
      size_t dst = (((size_t)sl * 96 + chunk) * 3 + gate) * 512 + u * 64 + b;
      xg[dst] = (_Float16)(acc[i][j] + biv[j]);
    }
  }
}

// ---------------------------------------------------------------------------
// Kernel B: persistent bidirectional GRU scan (one chunk of nsteps).
// 192 blocks: [0,96)=fwd, [96,192)=bwd; block owns 8 hidden units (24 Wh rows
// fp16 in LDS). Per step: k-split-8 fdot2 matvec + shfl reduce, fp32 gates,
// device-scope atomic barrier per direction per global step.
// h transposed [k][b]: fp16 operand + fp32 master, double-buffered by global
// step parity (persists across chunk launches).
// ---------------------------------------------------------------------------
__global__ __launch_bounds__(256) void scan_kernel(
    const float* __restrict__ Wh_f, const float* __restrict__ bh_f,
    const float* __restrict__ Wh_b, const float* __restrict__ bh_b,
    const _Float16* __restrict__ xg_f, const _Float16* __restrict__ xg_b,
    _Float16* __restrict__ h16, float* __restrict__ h32,
    unsigned* __restrict__ bars, int step0, int nsteps)
{
  const int blk = blockIdx.x;
  const int dir = blk / 96;
  const int g   = blk - dir * 96;
  const int j0  = g * 8;
  const float* __restrict__ Wh = dir ? Wh_b : Wh_f;
  const float* __restrict__ bh = dir ? bh_b : bh_f;
  const _Float16* __restrict__ xg = dir ? xg_b : xg_f;
  _Float16* __restrict__ h16d = h16 + (size_t)dir * 2 * HID * BATCH;
  float*    __restrict__ h32d = h32 + (size_t)dir * 2 * HID * BATCH;
  unsigned* __restrict__ bar  = bars + dir * 512;

  __shared__ _Float16 WhS[24][768];   // rows: gate*8 + u
  __shared__ float hgS[24][64];
  __shared__ float bhS[24];

  const int tid = threadIdx.x;
  for (int r = 0; r < 24; ++r) {
    int gate = r >> 3, u = r & 7;
    const float* wrow = Wh + (size_t)(gate * 768 + j0 + u) * 768;
    for (int k = tid; k < 768; k += 256) WhS[r][k] = (_Float16)wrow[k];
  }
  if (tid < 24) bhS[tid] = bh[(tid >> 3) * 768 + j0 + (tid & 7)];
  __syncthreads();

  const int wv = tid >> 6;        // wave 0..3 -> rows wv*6 .. wv*6+5
  const int lane = tid & 63;
  const int ks = lane >> 3;       // k-split 0..7
  const int bg = lane & 7;        // batch group 0..7 (8 b each)

  for (int t = 0; t < nsteps; ++t) {
    const int sg  = step0 + t;        // global step
    const int cur = sg & 1, nxt = cur ^ 1;
    const _Float16* __restrict__ hc = h16d + (size_t)cur * HID * BATCH; // [k][b]

    float acc[6][8];
#pragma unroll
    for (int i = 0; i < 6; ++i)
#pragma unroll
      for (int j = 0; j < 8; ++j) acc[i][j] = 0.f;

#pragma unroll 2
    for (int it = 0; it < 48; ++it) {
      const int pp = ks + it * 8;          // k-pair index, k = 2*pp
      h8 v0 = *(const h8*)&hc[(size_t)(2 * pp) * 64 + bg * 8];
      h8 v1 = *(const h8*)&hc[(size_t)(2 * pp + 1) * 64 + bg * 8];
      h2 wvv[6];
#pragma unroll
      for (int i = 0; i < 6; ++i) wvv[i] = *(const h2*)&WhS[wv * 6 + i][2 * pp];
      h2 hv[8];
#pragma unroll
      for (int j = 0; j < 8; ++j) hv[j] = mk2h(v0[j], v1[j]);
#pragma unroll
      for (int i = 0; i < 6; ++i)
#pragma unroll
        for (int j = 0; j < 8; ++j)
          acc[i][j] = __builtin_amdgcn_fdot2(wvv[i], hv[j], acc[i][j], false);
    }

    // reduce over the 8-way k-split (lane bits 3,4,5)
#pragma unroll
    for (int i = 0; i < 6; ++i)
#pragma unroll
      for (int j = 0; j < 8; ++j) {
        float v = acc[i][j];
        v += __shfl_xor(v, 8, 64);
        v += __shfl_xor(v, 16, 64);
        v += __shfl_xor(v, 32, 64);
        acc[i][j] = v;
      }
#pragma unroll
    for (int i = 0; i < 6; ++i)
      if (ks == i) {
#pragma unroll
        for (int j = 0; j < 8; ++j) hgS[wv * 6 + i][bg * 8 + j] = acc[i][j];
      }
    __syncthreads();

    // chunk-local xg row: fwd consumes t, bwd consumes nsteps-1-t
    const int lsl = dir ? (nsteps - 1 - t) : t;
    const size_t xbase = ((size_t)lsl * 96 + g) * 1536;
#pragma unroll
    for (int tt = 0; tt < 2; ++tt) {
      int t2 = tid + tt * 256;
      int u = t2 >> 6, b = t2 & 63;
      float xr = (float)xg[xbase + u * 64 + b];
      float xz = (float)xg[xbase + 512 + u * 64 + b];
      float xn = (float)xg[xbase + 1024 + u * 64 + b];
      float hr = hgS[u][b] + bhS[u];
      float hz = hgS[8 + u][b] + bhS[8 + u];
      float hn = hgS[16 + u][b] + bhS[16 + u];
      float rg = 1.f / (1.f + __expf(-(xr + hr)));
      float zg = 1.f / (1.f + __expf(-(xz + hz)));
      float ng = tanhf(xn + rg * hn);
      int hidx = (j0 + u) * 64 + b;
      float hp = h32d[(size_t)cur * HID * BATCH + hidx];
      float hnew = (1.f - zg) * ng + zg * hp;
      h32d[(size_t)nxt * HID * BATCH + hidx] = hnew;
      h16d[(size_t)nxt * HID * BATCH + hidx] = (_Float16)hnew;
    }
    __syncthreads();
    if (tid == 0) {
      __threadfence();                       // release our h writes (agent scope)
      atomicAdd(&bar[sg], 1u);
      while (__hip_atomic_load(&bar[sg], __ATOMIC_RELAXED, __HIP_MEMORY_SCOPE_AGENT) < 96u) { }
      __threadfence();                       // acquire side (conservative)
    }
    __syncthreads();
  }
}

// ---------------------------------------------------------------------------
// MLP head
// ---------------------------------------------------------------------------
__global__ __launch_bounds__(256) void mlp1_kernel(
    const float* __restrict__ h32, const float* __restrict__ W1,
    const float* __restrict__ b1, float* __restrict__ hid)
{
  const int c = blockIdx.x * 4 + (threadIdx.x >> 6);
  const int b = threadIdx.x & 63;
  const float* __restrict__ hf = h32 + b;                       // dir0 buf0 [k][b]
  const float* __restrict__ hb = h32 + 2 * HID * BATCH + b;     // dir1 buf0
  const float* __restrict__ w = W1 + (size_t)c * 1536;
  float acc = b1[c];
  for (int k = 0; k < 768; k += 4) {
    float4 wv = *(const float4*)&w[k];
    acc += hf[(k + 0) * 64] * wv.x + hf[(k + 1) * 64] * wv.y
         + hf[(k + 2) * 64] * wv.z + hf[(k + 3) * 64] * wv.w;
  }
  for (int k = 0; k < 768; k += 4) {
    float4 wv = *(const float4*)&w[768 + k];
    acc += hb[(k + 0) * 64] * wv.x + hb[(k + 1) * 64] * wv.y
         + hb[(k + 2) * 64] * wv.z + hb[(k + 3) * 64] * wv.w;
  }
  hid[(size_t)c * 64 + b] = fmaxf(acc, 0.f);
}

__global__ void mlp2_kernel(const float* __restrict__ hid,
                            const float* __restrict__ W2,
                            const float* __restrict__ b2,
                            float* __restrict__ out)
{
  const int tid = threadIdx.x;      // 128 threads
  const int b = tid & 63, cls = tid >> 6;
  const float* __restrict__ w = W2 + cls * 768;
  float acc = b2[cls];
  for (int k = 0; k < 768; ++k) acc += hid[(size_t)k * 64 + b] * w[k];
  out[b * 2 + cls] = acc;
}

// ---------------------------------------------------------------------------
extern "C" void kernel_launch(void* const* d_in, const int* in_sizes, int n_in,
                              void* d_out, int out_size, void* d_ws, size_t ws_size,
                              hipStream_t stream)
{
  const int*   ids  = (const int*)d_in[0];
  const float* emb  = (const float*)d_in[1];
  const float* Wi_f = (const float*)d_in[2];
  const float* Wh_f = (const float*)d_in[3];
  const float* bi_f = (const float*)d_in[4];
  const float* bh_f = (const float*)d_in[5];
  const float* Wi_b = (const float*)d_in[6];
  const float* Wh_b = (const float*)d_in[7];
  const float* bi_b = (const float*)d_in[8];
  const float* bh_b = (const float*)d_in[9];
  const float* W1   = (const float*)d_in[10];
  const float* b1   = (const float*)d_in[11];
  const float* W2   = (const float*)d_in[12];
  const float* b2   = (const float*)d_in[13];
  float* out = (float*)d_out;

  // state sizes (elements)
  const size_t N_H16 = (size_t)2 * 2 * HID * BATCH;   // halves
  const size_t N_H32 = (size_t)2 * 2 * HID * BATCH;   // floats
  const size_t N_HID = (size_t)HID * BATCH;           // floats
  const size_t N_BAR = 2 * 512;                       // uints
  const size_t state_bytes = N_H16 * 2 + N_H32 * 4 + N_HID * 4 + N_BAR * 4;

  // choose chunk size: largest CH with 2*CH*64*2304 fp16 xg + state <= ws
  int CH = 512;
  while (CH > 8) {
    size_t need = (size_t)4 * CH * 64 * 2304 + state_bytes;
    if (need <= ws_size) break;
    CH >>= 1;
  }
  const size_t SZ_XG = (size_t)CH * 64 * 2304;        // halves per direction

  char* ws = (char*)d_ws;
  _Float16* xg_f = (_Float16*)ws;
  _Float16* xg_b = xg_f + SZ_XG;
  _Float16* h16  = xg_b + SZ_XG;
  float*    h32  = (float*)(h16 + N_H16);
  float*    hid  = h32 + N_H32;
  unsigned* bars = (unsigned*)(hid + N_HID);

  // zero h16 + h32 + hid + barriers (contiguous region)
  size_t zbytes = N_H16 * 2 + N_H32 * 4 + N_HID * 4 + N_BAR * 4;
  (void)hipMemsetAsync(h16, 0, zbytes, stream);

  const int nch = 512 / CH;
  for (int c = 0; c < nch; ++c) {
    const int s0f = c * CH;                 // fwd window start
    const int s0b = 512 - (c + 1) * CH;     // bwd window start
    gemm1_kernel<<<dim3(CH / 2, 36), 256, 0, stream>>>(
        ids, emb, Wi_f, bi_f, Wi_b, bi_b, s0f, s0b, xg_f, xg_b);
    scan_kernel<<<192, 256, 0, stream>>>(
        Wh_f, bh_f, Wh_b, bh_b, xg_f, xg_b, h16, h32, bars, c * CH, CH);
  }
  mlp1_kernel<<<192, 256, 0, stream>>>(h32, W1, b1, hid);
  mlp2_kernel<<<1, 128, 0, stream>>>(hid, W2, b2, out);
}